// Round 9
// baseline (3722.537 us; speedup 1.0000x reference)
//
#include <hip/hip_runtime.h>

#define TT 512
#define BB 64
#define EMB 512
#define HID 1024
#define K4 1536
#define NBLK 256
#define THREADS 256

typedef __bf16 bf16x8 __attribute__((ext_vector_type(8)));
typedef float f32x4 __attribute__((ext_vector_type(4)));

__device__ __forceinline__ unsigned short f2bf(float f) {
    union { float f; unsigned u; } v; v.f = f;
    unsigned u = v.u;
    unsigned r = u + 0x7FFFu + ((u >> 16) & 1u);
    return (unsigned short)(r >> 16);
}

__global__ void zero_kernel(unsigned* p, int n) {
    int i = blockIdx.x * 256 + threadIdx.x;
    if (i < n) p[i] = 0u;
}

// Gather embedding rows, cast to bf16: xe_all[t][b][0:512]
__global__ void xe_kernel(const int* __restrict__ x, const float* __restrict__ emb,
                          unsigned short* __restrict__ xe_all) {
    int rowid = blockIdx.x;            // t*64 + b
    int t = rowid >> 6, b = rowid & 63;
    int idx = x[b * TT + t];
    float4 v = ((const float4*)(emb + (long)idx * EMB))[threadIdx.x];
    ushort4 o;
    o.x = f2bf(v.x); o.y = f2bf(v.y); o.z = f2bf(v.z); o.w = f2bf(v.w);
    ((ushort4*)(xe_all + (long)rowid * EMB))[threadIdx.x] = o;
}

// Wpack[n][k] bf16, n in [0,4096): gate=n>>10, col=n&1023; k<512 from Wx_gate, else Wh_gate.
__global__ void wpack_kernel(const float* __restrict__ Wxi, const float* __restrict__ Whi,
                             const float* __restrict__ Wxf, const float* __restrict__ Whf,
                             const float* __restrict__ Wxc, const float* __restrict__ Whc,
                             const float* __restrict__ Wxo, const float* __restrict__ Who,
                             unsigned short* __restrict__ Wpack) {
    const float* Wx[4] = {Wxi, Wxf, Wxc, Wxo};
    const float* Wh[4] = {Whi, Whf, Whc, Who};
    int n0 = (blockIdx.x & 15) << 8;       // 0..3840 step 256
    int k0 = (blockIdx.x >> 4) << 3;       // 0..1528 step 8
    int g = n0 >> 10, col0 = n0 & 1023;
    const float* base = (k0 < 512) ? (Wx[g] + (long)k0 * HID + col0)
                                   : (Wh[g] + (long)(k0 - 512) * HID + col0);
    int tid = threadIdx.x;
    union { unsigned short s[8]; uint4 v; } out;
#pragma unroll
    for (int i = 0; i < 8; ++i) out.s[i] = f2bf(base[(long)i * HID + tid]);
    *(uint4*)(Wpack + (long)(n0 + tid) * K4 + k0) = out.v;
}

#define MFMA(a, b, c) __builtin_amdgcn_mfma_f32_16x16x32_bf16((a), (b), (c), 0, 0, 0)

__launch_bounds__(THREADS, 1)
__global__ void lstm_kernel(const unsigned short* __restrict__ xe_all,
                            const unsigned short* __restrict__ Wpack,
                            unsigned short* __restrict__ hbuf,   // [2][64][1024] bf16
                            float* __restrict__ hfinal,          // [64][1024] f32
                            unsigned* __restrict__ arrive,       // [512*16*16] (16 lines/step)
                            const float* __restrict__ bi_p, const float* __restrict__ bf_p,
                            const float* __restrict__ bc_p, const float* __restrict__ bo_p) {
    // W tile in LDS, XOR-swizzled at 16B-block granularity:
    // chunk (c, bk) at block index c*192 + (bk ^ (c&7)); row stride 1536.
    __shared__ unsigned short Wlds[32 * 1536];
    __shared__ float partials[4][32][34];           // [kslice][m_local][c]

    const int tid = threadIdx.x;
    const int wave = tid >> 6, lane = tid & 63;
    const int quad = lane >> 4, r16 = lane & 15;
    const int ks4 = wave;              // k-slice (4 waves)
    const int bid = blockIdx.x;
    const int half = bid & 1;          // batch half: rows half*32..+32
    const int j0 = (bid >> 1) * 8;     // hidden slice [j0, j0+8)

    // ---- load W slice (32 gate-cols x 1536) into LDS, once, swizzled ----
#pragma unroll
    for (int i = 0; i < 24; ++i) {
        int gidx = tid + i * THREADS;          // 0..6143
        int c = gidx / 192, q = gidx % 192;
        int n = ((c >> 3) << 10) + j0 + (c & 7);
        *(uint4*)(&Wlds[(c * 192 + (q ^ (c & 7))) * 8]) =
            *(const uint4*)(Wpack + (long)n * K4 + q * 8);
    }
    const int b_loc = tid >> 3, jj = tid & 7;   // (local row, hidden col)
    const int b_ = half * 32 + b_loc;
    float rb0 = bi_p[j0 + jj], rb1 = bf_p[j0 + jj], rb2 = bc_p[j0 + jj], rb3 = bo_p[j0 + jj];
    float c_state = 0.f;
    __syncthreads();

    const f32x4 zf = {0.f, 0.f, 0.f, 0.f};
    const int row0 = half * 32 + r16;          // A rows row0 and row0+16
    const int s0 = r16 & 7;                    // XOR key for B rows r16 / 16+r16

    for (int t = 0; t < TT; ++t) {
        const unsigned short* xe_t = xe_all + (long)t * (BB * EMB);
        const unsigned short* hb = hbuf + (t & 1) * (BB * HID);

        f32x4 acc00 = zf, acc01 = zf, acc10 = zf, acc11 = zf;

        // ---- Phase X: xe part (k < 512), no cross-block dependency ----
        {
            uint4 xa[4][2];
#pragma unroll
            for (int i = 0; i < 4; ++i) {
                int k = ks4 * 128 + i * 32 + quad * 8;
                xa[i][0] = *(const uint4*)(xe_t + (long)row0 * EMB + k);
                xa[i][1] = *(const uint4*)(xe_t + (long)(row0 + 16) * EMB + k);
            }
#pragma unroll
            for (int i = 0; i < 4; ++i) {
                int bk = (ks4 * 128 + i * 32 + quad * 8) >> 3;
                bf16x8 b0 = *(const bf16x8*)(&Wlds[(r16 * 192 + (bk ^ s0)) * 8]);
                bf16x8 b1 = *(const bf16x8*)(&Wlds[((16 + r16) * 192 + (bk ^ s0)) * 8]);
                bf16x8 a0 = __builtin_bit_cast(bf16x8, xa[i][0]);
                bf16x8 a1 = __builtin_bit_cast(bf16x8, xa[i][1]);
                acc00 = MFMA(a0, b0, acc00); acc01 = MFMA(a0, b1, acc01);
                acc10 = MFMA(a1, b0, acc10); acc11 = MFMA(a1, b1, acc11);
            }
        }

        // ---- wait for h_t of OUR half, then invalidate L1/L2 so cached
        //      h loads see the fresh LLC data (one fence per block) ----
        if (t > 0 && wave == 0) {
            const unsigned* fp = &arrive[((t - 1) * 16 + half * 8 + (lane & 7)) * 16];
            while (!__all(__hip_atomic_load(fp, __ATOMIC_RELAXED,
                                            __HIP_MEMORY_SCOPE_AGENT) >= 16u))
                __builtin_amdgcn_s_sleep(2);
            __builtin_amdgcn_fence(__ATOMIC_ACQUIRE, "agent");   // buffer_inv (L1+L2)
            asm volatile("s_waitcnt vmcnt(0)" ::: "memory");     // inval done pre-barrier
        }
        __syncthreads();
        asm volatile("" ::: "memory");   // no load hoisting above the barrier

        // ---- Phase H: h part (k >= 512), normal cached loads (L2-shared per XCD) ----
        {
            uint4 ha[8][2];
#pragma unroll
            for (int i = 0; i < 8; ++i) {
                const unsigned short* p0 = hb + (long)row0 * HID + ks4 * 256 + i * 32 + quad * 8;
                ha[i][0] = *(const uint4*)p0;
                ha[i][1] = *(const uint4*)(p0 + 16 * HID);
            }
#pragma unroll
            for (int i = 0; i < 8; ++i) {
                int bk = (512 + ks4 * 256 + i * 32 + quad * 8) >> 3;
                bf16x8 b0 = *(const bf16x8*)(&Wlds[(r16 * 192 + (bk ^ s0)) * 8]);
                bf16x8 b1 = *(const bf16x8*)(&Wlds[((16 + r16) * 192 + (bk ^ s0)) * 8]);
                bf16x8 a0 = __builtin_bit_cast(bf16x8, ha[i][0]);
                bf16x8 a1 = __builtin_bit_cast(bf16x8, ha[i][1]);
                acc00 = MFMA(a0, b0, acc00); acc01 = MFMA(a0, b1, acc01);
                acc10 = MFMA(a1, b0, acc10); acc11 = MFMA(a1, b1, acc11);
            }
        }

        // ---- partials (C layout: col=lane&15, row=(lane>>4)*4+reg), m_local 0..31 ----
        {
            int pr0 = quad * 4;
#pragma unroll
            for (int rr = 0; rr < 4; ++rr) {
                partials[ks4][pr0 + rr][r16]           = acc00[rr];
                partials[ks4][pr0 + rr][16 + r16]      = acc01[rr];
                partials[ks4][pr0 + 16 + rr][r16]      = acc10[rr];
                partials[ks4][pr0 + 16 + rr][16 + r16] = acc11[rr];
            }
        }
        __syncthreads();

        // ---- elementwise: thread -> (b_loc, jj) ----
        float gi = 0.f, gf = 0.f, gc = 0.f, go = 0.f;
#pragma unroll
        for (int w = 0; w < 4; ++w) {
            gi += partials[w][b_loc][jj];
            gf += partials[w][b_loc][8 + jj];
            gc += partials[w][b_loc][16 + jj];
            go += partials[w][b_loc][24 + jj];
        }
        gi += rb0; gf += rb1; gc += rb2; go += rb3;
        float si = 1.f / (1.f + __expf(-gi));
        float sf = 1.f / (1.f + __expf(-gf));
        float so = 1.f / (1.f + __expf(-go));
        float e2 = __expf(2.f * gc); float tc = (e2 - 1.f) / (e2 + 1.f);
        float c = sf * c_state + si * tc;
        c_state = c;
        float e2c = __expf(2.f * c); float th = (e2c - 1.f) / (e2c + 1.f);
        float h = so * th;

        unsigned short hv = f2bf(h);
        const unsigned short* hop = hbuf + ((t + 1) & 1) * (BB * HID) + b_ * HID + j0 + jj;
        asm volatile("global_store_short %0, %1, off sc1" :: "v"(hop), "v"(hv) : "memory");
        if (t == TT - 1) hfinal[b_ * HID + j0 + jj] = h;
        asm volatile("s_waitcnt vmcnt(0)" ::: "memory");   // h at LLC before arrive
        __syncthreads();
        if (tid == 0)
            __hip_atomic_fetch_add(&arrive[(t * 16 + half * 8 + ((bid >> 1) & 7)) * 16], 1u,
                                   __ATOMIC_RELAXED, __HIP_MEMORY_SCOPE_AGENT);
    }
}

// y[b][o] = dot(hfinal[b], Why[:,o]) + by[o]; one wave per output
__global__ void out_kernel(const float* __restrict__ hfinal, const float* __restrict__ Why,
                           const float* __restrict__ by, float* __restrict__ y) {
    int gw = blockIdx.x * 4 + (threadIdx.x >> 6);
    int lane = threadIdx.x & 63;
    int b = gw >> 1, o = gw & 1;
    float s = 0.f;
    for (int k = lane; k < HID; k += 64) s += hfinal[b * HID + k] * Why[k * 2 + o];
#pragma unroll
    for (int off = 32; off; off >>= 1) s += __shfl_down(s, off);
    if (lane == 0) y[b * 2 + o] = s + by[o];
}

extern "C" void kernel_launch(void* const* d_in, const int* in_sizes, int n_in,
                              void* d_out, int out_size, void* d_ws, size_t ws_size,
                              hipStream_t stream) {
    const int*   x   = (const int*)d_in[0];
    const float* emb = (const float*)d_in[1];
    const float* Wxi = (const float*)d_in[2];
    const float* Whi = (const float*)d_in[3];
    const float* bi  = (const float*)d_in[4];
    const float* Wxf = (const float*)d_in[5];
    const float* Whf = (const float*)d_in[6];
    const float* bfp = (const float*)d_in[7];
    const float* Wxc = (const float*)d_in[8];
    const float* Whc = (const float*)d_in[9];
    const float* bc  = (const float*)d_in[10];
    const float* Wxo = (const float*)d_in[11];
    const float* Who = (const float*)d_in[12];
    const float* bo  = (const float*)d_in[13];
    const float* Why = (const float*)d_in[14];
    const float* by  = (const float*)d_in[15];
    float* y = (float*)d_out;

    char* ws = (char*)d_ws;
    // layout: Wpack 12,582,912 | xe_all 33,554,432 | hbuf 262,144 | arrive 524,288 | hfinal 262,144
    unsigned short* Wpack  = (unsigned short*)ws;
    unsigned short* xe_all = (unsigned short*)(ws + 12582912);
    unsigned short* hbuf   = (unsigned short*)(ws + 12582912 + 33554432);
    unsigned*       arrive = (unsigned*)(ws + 12582912 + 33554432 + 262144);
    float*          hfinal = (float*)(ws + 12582912 + 33554432 + 262144 + 524288);

    // zero hbuf (65536 u32) + arrive (131072 u32), contiguous
    zero_kernel<<<768, 256, 0, stream>>>((unsigned*)hbuf, 196608);
    wpack_kernel<<<3072, 256, 0, stream>>>(Wxi, Whi, Wxf, Whf, Wxc, Whc, Wxo, Who, Wpack);
    xe_kernel<<<32768, 128, 0, stream>>>(x, emb, xe_all);

    const unsigned short* xe_p = xe_all;
    const unsigned short* Wp_p = Wpack;
    unsigned short* hb_p = hbuf;
    float* hf_p = hfinal;
    unsigned* ar_p = arrive;
    void* args[] = {&xe_p, &Wp_p, &hb_p, &hf_p, &ar_p,
                    (void*)&bi, (void*)&bfp, (void*)&bc, (void*)&bo};
    hipLaunchCooperativeKernel((void*)lstm_kernel, dim3(NBLK), dim3(THREADS), args, 0, stream);

    out_kernel<<<32, 256, 0, stream>>>(hfinal, Why, by, y);
}

// Round 10
// 2625.978 us; speedup vs baseline: 1.4176x; 1.4176x over previous
//
#include <hip/hip_runtime.h>

#define TT 512
#define BB 64
#define EMB 512
#define HID 1024
#define K4 1536
#define NBLK 256
#define THREADS 256

typedef __bf16 bf16x8 __attribute__((ext_vector_type(8)));
typedef float f32x4 __attribute__((ext_vector_type(4)));

__device__ __forceinline__ unsigned short f2bf(float f) {
    union { float f; unsigned u; } v; v.f = f;
    unsigned u = v.u;
    unsigned r = u + 0x7FFFu + ((u >> 16) & 1u);
    return (unsigned short)(r >> 16);
}

__global__ void zero_kernel(unsigned* p, int n) {
    int i = blockIdx.x * 256 + threadIdx.x;
    if (i < n) p[i] = 0u;
}

// Gather embedding rows, cast to bf16: xe_all[t][b][0:512]
__global__ void xe_kernel(const int* __restrict__ x, const float* __restrict__ emb,
                          unsigned short* __restrict__ xe_all) {
    int rowid = blockIdx.x;            // t*64 + b
    int t = rowid >> 6, b = rowid & 63;
    int idx = x[b * TT + t];
    float4 v = ((const float4*)(emb + (long)idx * EMB))[threadIdx.x];
    ushort4 o;
    o.x = f2bf(v.x); o.y = f2bf(v.y); o.z = f2bf(v.z); o.w = f2bf(v.w);
    ((ushort4*)(xe_all + (long)rowid * EMB))[threadIdx.x] = o;
}

// Wpack[n][k] bf16, n in [0,4096): gate=n>>10, col=n&1023; k<512 from Wx_gate, else Wh_gate.
__global__ void wpack_kernel(const float* __restrict__ Wxi, const float* __restrict__ Whi,
                             const float* __restrict__ Wxf, const float* __restrict__ Whf,
                             const float* __restrict__ Wxc, const float* __restrict__ Whc,
                             const float* __restrict__ Wxo, const float* __restrict__ Who,
                             unsigned short* __restrict__ Wpack) {
    const float* Wx[4] = {Wxi, Wxf, Wxc, Wxo};
    const float* Wh[4] = {Whi, Whf, Whc, Who};
    int n0 = (blockIdx.x & 15) << 8;       // 0..3840 step 256
    int k0 = (blockIdx.x >> 4) << 3;       // 0..1528 step 8
    int g = n0 >> 10, col0 = n0 & 1023;
    const float* base = (k0 < 512) ? (Wx[g] + (long)k0 * HID + col0)
                                   : (Wh[g] + (long)(k0 - 512) * HID + col0);
    int tid = threadIdx.x;
    union { unsigned short s[8]; uint4 v; } out;
#pragma unroll
    for (int i = 0; i < 8; ++i) out.s[i] = f2bf(base[(long)i * HID + tid]);
    *(uint4*)(Wpack + (long)(n0 + tid) * K4 + k0) = out.v;
}

#define MFMA(a, b, c) __builtin_amdgcn_mfma_f32_16x16x32_bf16((a), (b), (c), 0, 0, 0)

__launch_bounds__(THREADS, 1)
__global__ void lstm_kernel(const unsigned short* __restrict__ xe_all,
                            const unsigned short* __restrict__ Wpack,
                            unsigned short* __restrict__ hbuf,   // [2][64][1024] bf16
                            float* __restrict__ hfinal,          // [64][1024] f32
                            unsigned* __restrict__ arrive,       // [512*16*16] (16 lines/step)
                            const float* __restrict__ bi_p, const float* __restrict__ bf_p,
                            const float* __restrict__ bc_p, const float* __restrict__ bo_p) {
    // W tile in LDS, XOR-swizzled at 16B-block granularity:
    // chunk (c, bk) at block index c*192 + (bk ^ (c&7)); row stride 1536.
    __shared__ unsigned short Wlds[32 * 1536];
    // partials[ks][c][m], m-stride 44: b128 writes are group-uniform, b32 reads 2-way.
    __shared__ __align__(16) float partials[4][32][44];

    const int tid = threadIdx.x;
    const int wave = tid >> 6, lane = tid & 63;
    const int quad = lane >> 4, r16 = lane & 15;
    const int ks4 = wave;              // k-slice (4 waves)
    const int bid = blockIdx.x;
    const int half = bid & 1;          // batch half: rows half*32..+32
    const int j0 = (bid >> 1) * 8;     // hidden slice [j0, j0+8)

    // ---- load W slice (32 gate-cols x 1536) into LDS, once, swizzled ----
#pragma unroll
    for (int i = 0; i < 24; ++i) {
        int gidx = tid + i * THREADS;          // 0..6143
        int c = gidx / 192, q = gidx % 192;
        int n = ((c >> 3) << 10) + j0 + (c & 7);
        *(uint4*)(&Wlds[(c * 192 + (q ^ (c & 7))) * 8]) =
            *(const uint4*)(Wpack + (long)n * K4 + q * 8);
    }
    const int b_loc = tid >> 3, jj = tid & 7;   // (local row, hidden col)
    const int b_ = half * 32 + b_loc;
    float rb0 = bi_p[j0 + jj], rb1 = bf_p[j0 + jj], rb2 = bc_p[j0 + jj], rb3 = bo_p[j0 + jj];
    float c_state = 0.f;
    __syncthreads();

    const f32x4 zf = {0.f, 0.f, 0.f, 0.f};
    const int row0 = half * 32 + r16;          // A rows row0 and row0+16
    const int s0 = r16 & 7;                    // XOR key for B rows r16 / 16+r16

    for (int t = 0; t < TT; ++t) {
        const unsigned short* xe_t = xe_all + (long)t * (BB * EMB);
        const unsigned short* hb = hbuf + (t & 1) * (BB * HID);

        f32x4 acc00 = zf, acc01 = zf, acc10 = zf, acc11 = zf;

        // ---- Phase X: xe part (k < 512), no cross-block dependency ----
        {
            uint4 xa[4][2];
#pragma unroll
            for (int i = 0; i < 4; ++i) {
                int k = ks4 * 128 + i * 32 + quad * 8;
                xa[i][0] = *(const uint4*)(xe_t + (long)row0 * EMB + k);
                xa[i][1] = *(const uint4*)(xe_t + (long)(row0 + 16) * EMB + k);
            }
#pragma unroll
            for (int i = 0; i < 4; ++i) {
                int bk = (ks4 * 128 + i * 32 + quad * 8) >> 3;
                bf16x8 b0 = *(const bf16x8*)(&Wlds[(r16 * 192 + (bk ^ s0)) * 8]);
                bf16x8 b1 = *(const bf16x8*)(&Wlds[((16 + r16) * 192 + (bk ^ s0)) * 8]);
                bf16x8 a0 = __builtin_bit_cast(bf16x8, xa[i][0]);
                bf16x8 a1 = __builtin_bit_cast(bf16x8, xa[i][1]);
                acc00 = MFMA(a0, b0, acc00); acc01 = MFMA(a0, b1, acc01);
                acc10 = MFMA(a1, b0, acc10); acc11 = MFMA(a1, b1, acc11);
            }
        }

        // ---- wait for h_t of OUR half: every wave self-polls the 8 shard lines ----
        if (t > 0) {
            const unsigned* fp = &arrive[((t - 1) * 16 + half * 8 + (lane & 7)) * 16];
            while (!__all(__hip_atomic_load(fp, __ATOMIC_RELAXED,
                                            __HIP_MEMORY_SCOPE_AGENT) >= 16u))
                __builtin_amdgcn_s_sleep(1);
            asm volatile("" ::: "memory");   // no load hoisting above the poll
        }

        // ---- Phase H: h part (k >= 512), device-scope (LLC) loads, all in flight ----
        {
            uint4 ha[8][2];
#pragma unroll
            for (int i = 0; i < 8; ++i) {
                const unsigned short* p0 = hb + (long)row0 * HID + ks4 * 256 + i * 32 + quad * 8;
                const unsigned short* p1 = p0 + 16 * HID;
                asm volatile("global_load_dwordx4 %0, %1, off sc1" : "=v"(ha[i][0]) : "v"(p0));
                asm volatile("global_load_dwordx4 %0, %1, off sc1" : "=v"(ha[i][1]) : "v"(p1));
            }
            asm volatile("s_waitcnt vmcnt(0)" ::: "memory");
#pragma unroll
            for (int i = 0; i < 8; ++i) {
                int bk = (512 + ks4 * 256 + i * 32 + quad * 8) >> 3;
                bf16x8 b0 = *(const bf16x8*)(&Wlds[(r16 * 192 + (bk ^ s0)) * 8]);
                bf16x8 b1 = *(const bf16x8*)(&Wlds[((16 + r16) * 192 + (bk ^ s0)) * 8]);
                bf16x8 a0 = __builtin_bit_cast(bf16x8, ha[i][0]);
                bf16x8 a1 = __builtin_bit_cast(bf16x8, ha[i][1]);
                acc00 = MFMA(a0, b0, acc00); acc01 = MFMA(a0, b1, acc01);
                acc10 = MFMA(a1, b0, acc10); acc11 = MFMA(a1, b1, acc11);
            }
        }

        // ---- partials: C col=lane&15 -> c-index; rows quad*4+reg -> m, b128 stores ----
        {
            int pr0 = quad * 4;
            *(f32x4*)&partials[ks4][r16][pr0]           = acc00;
            *(f32x4*)&partials[ks4][16 + r16][pr0]      = acc01;
            *(f32x4*)&partials[ks4][r16][pr0 + 16]      = acc10;
            *(f32x4*)&partials[ks4][16 + r16][pr0 + 16] = acc11;
        }
        __syncthreads();

        // ---- elementwise: thread -> (b_loc, jj); reads are 2-way (free) ----
        float gi = 0.f, gf = 0.f, gc = 0.f, go = 0.f;
#pragma unroll
        for (int w = 0; w < 4; ++w) {
            gi += partials[w][jj][b_loc];
            gf += partials[w][8 + jj][b_loc];
            gc += partials[w][16 + jj][b_loc];
            go += partials[w][24 + jj][b_loc];
        }
        gi += rb0; gf += rb1; gc += rb2; go += rb3;
        float si = 1.f / (1.f + __expf(-gi));
        float sf = 1.f / (1.f + __expf(-gf));
        float so = 1.f / (1.f + __expf(-go));
        float e2 = __expf(2.f * gc); float tc = (e2 - 1.f) / (e2 + 1.f);
        float c = sf * c_state + si * tc;
        c_state = c;
        float e2c = __expf(2.f * c); float th = (e2c - 1.f) / (e2c + 1.f);
        float h = so * th;

        unsigned short hv = f2bf(h);
        const unsigned short* hop = hbuf + ((t + 1) & 1) * (BB * HID) + b_ * HID + j0 + jj;
        asm volatile("global_store_short %0, %1, off sc1" :: "v"(hop), "v"(hv) : "memory");
        if (t == TT - 1) hfinal[b_ * HID + j0 + jj] = h;
        asm volatile("s_waitcnt vmcnt(0)" ::: "memory");   // h at LLC before arrive
        __syncthreads();
        if (tid == 0)
            __hip_atomic_fetch_add(&arrive[(t * 16 + half * 8 + ((bid >> 1) & 7)) * 16], 1u,
                                   __ATOMIC_RELAXED, __HIP_MEMORY_SCOPE_AGENT);
    }
}

// y[b][o] = dot(hfinal[b], Why[:,o]) + by[o]; one wave per output
__global__ void out_kernel(const float* __restrict__ hfinal, const float* __restrict__ Why,
                           const float* __restrict__ by, float* __restrict__ y) {
    int gw = blockIdx.x * 4 + (threadIdx.x >> 6);
    int lane = threadIdx.x & 63;
    int b = gw >> 1, o = gw & 1;
    float s = 0.f;
    for (int k = lane; k < HID; k += 64) s += hfinal[b * HID + k] * Why[k * 2 + o];
#pragma unroll
    for (int off = 32; off; off >>= 1) s += __shfl_down(s, off);
    if (lane == 0) y[b * 2 + o] = s + by[o];
}

extern "C" void kernel_launch(void* const* d_in, const int* in_sizes, int n_in,
                              void* d_out, int out_size, void* d_ws, size_t ws_size,
                              hipStream_t stream) {
    const int*   x   = (const int*)d_in[0];
    const float* emb = (const float*)d_in[1];
    const float* Wxi = (const float*)d_in[2];
    const float* Whi = (const float*)d_in[3];
    const float* bi  = (const float*)d_in[4];
    const float* Wxf = (const float*)d_in[5];
    const float* Whf = (const float*)d_in[6];
    const float* bfp = (const float*)d_in[7];
    const float* Wxc = (const float*)d_in[8];
    const float* Whc = (const float*)d_in[9];
    const float* bc  = (const float*)d_in[10];
    const float* Wxo = (const float*)d_in[11];
    const float* Who = (const float*)d_in[12];
    const float* bo  = (const float*)d_in[13];
    const float* Why = (const float*)d_in[14];
    const float* by  = (const float*)d_in[15];
    float* y = (float*)d_out;

    char* ws = (char*)d_ws;
    // layout: Wpack 12,582,912 | xe_all 33,554,432 | hbuf 262,144 | arrive 524,288 | hfinal 262,144
    unsigned short* Wpack  = (unsigned short*)ws;
    unsigned short* xe_all = (unsigned short*)(ws + 12582912);
    unsigned short* hbuf   = (unsigned short*)(ws + 12582912 + 33554432);
    unsigned*       arrive = (unsigned*)(ws + 12582912 + 33554432 + 262144);
    float*          hfinal = (float*)(ws + 12582912 + 33554432 + 262144 + 524288);

    // zero hbuf (65536 u32) + arrive (131072 u32), contiguous
    zero_kernel<<<768, 256, 0, stream>>>((unsigned*)hbuf, 196608);
    wpack_kernel<<<3072, 256, 0, stream>>>(Wxi, Whi, Wxf, Whf, Wxc, Whc, Wxo, Who, Wpack);
    xe_kernel<<<32768, 128, 0, stream>>>(x, emb, xe_all);

    const unsigned short* xe_p = xe_all;
    const unsigned short* Wp_p = Wpack;
    unsigned short* hb_p = hbuf;
    float* hf_p = hfinal;
    unsigned* ar_p = arrive;
    void* args[] = {&xe_p, &Wp_p, &hb_p, &hf_p, &ar_p,
                    (void*)&bi, (void*)&bfp, (void*)&bc, (void*)&bo};
    hipLaunchCooperativeKernel((void*)lstm_kernel, dim3(NBLK), dim3(THREADS), args, 0, stream);

    out_kernel<<<32, 256, 0, stream>>>(hfinal, Why, by, y);
}

// Round 11
// 2412.480 us; speedup vs baseline: 1.5430x; 1.0885x over previous
//
#include <hip/hip_runtime.h>

#define TT 512
#define BB 64
#define EMB 512
#define HID 1024
#define K4 1536
#define NBLK 256
#define THREADS 512

typedef __bf16 bf16x8 __attribute__((ext_vector_type(8)));
typedef float f32x4 __attribute__((ext_vector_type(4)));

__device__ __forceinline__ unsigned short f2bf(float f) {
    union { float f; unsigned u; } v; v.f = f;
    unsigned u = v.u;
    unsigned r = u + 0x7FFFu + ((u >> 16) & 1u);
    return (unsigned short)(r >> 16);
}

__global__ void zero_kernel(unsigned* p, int n) {
    int i = blockIdx.x * 256 + threadIdx.x;
    if (i < n) p[i] = 0u;
}

// Gather embedding rows, cast to bf16: xe_all[t][b][0:512]
__global__ void xe_kernel(const int* __restrict__ x, const float* __restrict__ emb,
                          unsigned short* __restrict__ xe_all) {
    int rowid = blockIdx.x;            // t*64 + b
    int t = rowid >> 6, b = rowid & 63;
    int idx = x[b * TT + t];
    float4 v = ((const float4*)(emb + (long)idx * EMB))[threadIdx.x];
    ushort4 o;
    o.x = f2bf(v.x); o.y = f2bf(v.y); o.z = f2bf(v.z); o.w = f2bf(v.w);
    ((ushort4*)(xe_all + (long)rowid * EMB))[threadIdx.x] = o;
}

// Wpack[n][k] bf16, n in [0,4096): gate=n>>10, col=n&1023; k<512 from Wx_gate, else Wh_gate.
__global__ void wpack_kernel(const float* __restrict__ Wxi, const float* __restrict__ Whi,
                             const float* __restrict__ Wxf, const float* __restrict__ Whf,
                             const float* __restrict__ Wxc, const float* __restrict__ Whc,
                             const float* __restrict__ Wxo, const float* __restrict__ Who,
                             unsigned short* __restrict__ Wpack) {
    const float* Wx[4] = {Wxi, Wxf, Wxc, Wxo};
    const float* Wh[4] = {Whi, Whf, Whc, Who};
    int n0 = (blockIdx.x & 15) << 8;       // 0..3840 step 256
    int k0 = (blockIdx.x >> 4) << 3;       // 0..1528 step 8
    int g = n0 >> 10, col0 = n0 & 1023;
    const float* base = (k0 < 512) ? (Wx[g] + (long)k0 * HID + col0)
                                   : (Wh[g] + (long)(k0 - 512) * HID + col0);
    int tid = threadIdx.x;
    union { unsigned short s[8]; uint4 v; } out;
#pragma unroll
    for (int i = 0; i < 8; ++i) out.s[i] = f2bf(base[(long)i * HID + tid]);
    *(uint4*)(Wpack + (long)(n0 + tid) * K4 + k0) = out.v;
}

#define MFMA(a, b, c) __builtin_amdgcn_mfma_f32_16x16x32_bf16((a), (b), (c), 0, 0, 0)

__launch_bounds__(THREADS, 2)
__global__ void lstm_kernel(const unsigned short* __restrict__ xe_all,
                            const unsigned short* __restrict__ Wpack,
                            unsigned short* __restrict__ hbuf,   // [2][64][1024] bf16
                            float* __restrict__ hfinal,          // [64][1024] f32
                            unsigned* __restrict__ arrive,       // [512*16*16] (16 lines/step)
                            const float* __restrict__ bi_p, const float* __restrict__ bf_p,
                            const float* __restrict__ bc_p, const float* __restrict__ bo_p) {
    // W tile in LDS, XOR-swizzled at 16B-block granularity:
    // chunk (c, bk) at block index c*192 + (bk ^ (c&7)); row stride 1536.
    __shared__ unsigned short Wlds[32 * 1536];
    // partials[ks][c][m], m-stride 44: b128 writes group-uniform, b32 reads 2-way.
    __shared__ __align__(16) float partials[4][32][44];

    const int tid = threadIdx.x;
    const int wave = tid >> 6, lane = tid & 63;
    const int quad = lane >> 4, r16 = lane & 15;
    const int ks4 = wave >> 1;         // k-slice (4 slices x 2 m-waves)
    const int mw = wave & 1;           // m-half within the 32 rows
    const int bid = blockIdx.x;
    const int half = bid & 1;          // batch half: rows half*32..+32
    const int pidx = bid >> 1;         // producer index within half (hidden slice)
    const int j0 = pidx * 8;           // hidden slice [j0, j0+8)

    // ---- load W slice (32 gate-cols x 1536) into LDS, once, swizzled ----
#pragma unroll
    for (int i = 0; i < 12; ++i) {
        int gidx = tid + i * THREADS;          // 0..6143
        int c = gidx / 192, q = gidx % 192;
        int n = ((c >> 3) << 10) + j0 + (c & 7);
        *(uint4*)(&Wlds[(c * 192 + (q ^ (c & 7))) * 8]) =
            *(const uint4*)(Wpack + (long)n * K4 + q * 8);
    }
    const int b_loc = (tid & 255) >> 3, jj = tid & 7;  // elementwise mapping (tid<256)
    const int b_ = half * 32 + b_loc;
    float rb0 = 0.f, rb1 = 0.f, rb2 = 0.f, rb3 = 0.f;
    if (tid < 256) {
        rb0 = bi_p[j0 + jj]; rb1 = bf_p[j0 + jj];
        rb2 = bc_p[j0 + jj]; rb3 = bo_p[j0 + jj];
    }
    float c_state = 0.f;
    __syncthreads();

    const f32x4 zf = {0.f, 0.f, 0.f, 0.f};
    const int row0 = half * 32 + mw * 16 + r16;   // this wave's 16 A rows
    const int s0 = r16 & 7;                       // XOR key for B rows r16 / 16+r16

    for (int t = 0; t < TT; ++t) {
        const unsigned short* xe_t = xe_all + (long)t * (BB * EMB);
        const unsigned short* hb = hbuf + (t & 1) * (BB * HID);

        f32x4 acc0 = zf, acc1 = zf;

        // ---- Phase X: xe part (k < 512), no cross-block dependency ----
        {
            uint4 xa[4];
#pragma unroll
            for (int i = 0; i < 4; ++i) {
                int k = ks4 * 128 + i * 32 + quad * 8;
                xa[i] = *(const uint4*)(xe_t + (long)row0 * EMB + k);
            }
#pragma unroll
            for (int i = 0; i < 4; ++i) {
                int bk = (ks4 * 128 + i * 32 + quad * 8) >> 3;
                bf16x8 b0 = *(const bf16x8*)(&Wlds[(r16 * 192 + (bk ^ s0)) * 8]);
                bf16x8 b1 = *(const bf16x8*)(&Wlds[((16 + r16) * 192 + (bk ^ s0)) * 8]);
                bf16x8 a0 = __builtin_bit_cast(bf16x8, xa[i]);
                acc0 = MFMA(a0, b0, acc0); acc1 = MFMA(a0, b1, acc1);
            }
        }

        // ---- wait for OUR k-slice's producers (2 shard lines of 16 each) ----
        if (t > 0) {
            const unsigned* fp = &arrive[((t - 1) * 16 + half * 8 + ks4 * 2 + (lane & 1)) * 16];
            while (!__all(__hip_atomic_load(fp, __ATOMIC_RELAXED,
                                            __HIP_MEMORY_SCOPE_AGENT) >= 16u))
                __builtin_amdgcn_s_sleep(1);
            asm volatile("" ::: "memory");   // no load hoisting above the poll
        }

        // ---- Phase H: h part (k >= 512), device-scope (LLC) loads, all in flight ----
        {
            uint4 ha[8];
#pragma unroll
            for (int i = 0; i < 8; ++i) {
                const unsigned short* p0 = hb + (long)row0 * HID + ks4 * 256 + i * 32 + quad * 8;
                asm volatile("global_load_dwordx4 %0, %1, off sc1" : "=v"(ha[i]) : "v"(p0));
            }
            asm volatile("s_waitcnt vmcnt(0)" ::: "memory");
#pragma unroll
            for (int i = 0; i < 8; ++i) {
                int bk = (512 + ks4 * 256 + i * 32 + quad * 8) >> 3;
                bf16x8 b0 = *(const bf16x8*)(&Wlds[(r16 * 192 + (bk ^ s0)) * 8]);
                bf16x8 b1 = *(const bf16x8*)(&Wlds[((16 + r16) * 192 + (bk ^ s0)) * 8]);
                bf16x8 a0 = __builtin_bit_cast(bf16x8, ha[i]);
                acc0 = MFMA(a0, b0, acc0); acc1 = MFMA(a0, b1, acc1);
            }
        }

        // ---- partials: C col -> c-index; m_local = mw*16 + quad*4 + reg, b128 stores ----
        {
            int pm = mw * 16 + quad * 4;
            *(f32x4*)&partials[ks4][r16][pm]      = acc0;
            *(f32x4*)&partials[ks4][16 + r16][pm] = acc1;
        }
        __syncthreads();

        // ---- elementwise: threads 0..255 -> (b_loc, jj); reads 2-way (free) ----
        if (tid < 256) {
            float gi = 0.f, gf = 0.f, gc = 0.f, go = 0.f;
#pragma unroll
            for (int w = 0; w < 4; ++w) {
                gi += partials[w][jj][b_loc];
                gf += partials[w][8 + jj][b_loc];
                gc += partials[w][16 + jj][b_loc];
                go += partials[w][24 + jj][b_loc];
            }
            gi += rb0; gf += rb1; gc += rb2; go += rb3;
            float si = 1.f / (1.f + __expf(-gi));
            float sf = 1.f / (1.f + __expf(-gf));
            float so = 1.f / (1.f + __expf(-go));
            float e2 = __expf(2.f * gc); float tc = (e2 - 1.f) / (e2 + 1.f);
            float c = sf * c_state + si * tc;
            c_state = c;
            float e2c = __expf(2.f * c); float th = (e2c - 1.f) / (e2c + 1.f);
            float h = so * th;
            unsigned short hv = f2bf(h);
            const unsigned short* hop = hbuf + ((t + 1) & 1) * (BB * HID) + b_ * HID + j0 + jj;
            asm volatile("global_store_short %0, %1, off sc1" :: "v"(hop), "v"(hv) : "memory");
            if (t == TT - 1) hfinal[b_ * HID + j0 + jj] = h;
        }
        asm volatile("s_waitcnt vmcnt(0)" ::: "memory");   // h at LLC before arrive
        __syncthreads();
        if (tid == 0)
            __hip_atomic_fetch_add(&arrive[(t * 16 + half * 8 + (pidx >> 4)) * 16], 1u,
                                   __ATOMIC_RELAXED, __HIP_MEMORY_SCOPE_AGENT);
    }
}

// y[b][o] = dot(hfinal[b], Why[:,o]) + by[o]; one wave per output
__global__ void out_kernel(const float* __restrict__ hfinal, const float* __restrict__ Why,
                           const float* __restrict__ by, float* __restrict__ y) {
    int gw = blockIdx.x * 4 + (threadIdx.x >> 6);
    int lane = threadIdx.x & 63;
    int b = gw >> 1, o = gw & 1;
    float s = 0.f;
    for (int k = lane; k < HID; k += 64) s += hfinal[b * HID + k] * Why[k * 2 + o];
#pragma unroll
    for (int off = 32; off; off >>= 1) s += __shfl_down(s, off);
    if (lane == 0) y[b * 2 + o] = s + by[o];
}

extern "C" void kernel_launch(void* const* d_in, const int* in_sizes, int n_in,
                              void* d_out, int out_size, void* d_ws, size_t ws_size,
                              hipStream_t stream) {
    const int*   x   = (const int*)d_in[0];
    const float* emb = (const float*)d_in[1];
    const float* Wxi = (const float*)d_in[2];
    const float* Whi = (const float*)d_in[3];
    const float* bi  = (const float*)d_in[4];
    const float* Wxf = (const float*)d_in[5];
    const float* Whf = (const float*)d_in[6];
    const float* bfp = (const float*)d_in[7];
    const float* Wxc = (const float*)d_in[8];
    const float* Whc = (const float*)d_in[9];
    const float* bc  = (const float*)d_in[10];
    const float* Wxo = (const float*)d_in[11];
    const float* Who = (const float*)d_in[12];
    const float* bo  = (const float*)d_in[13];
    const float* Why = (const float*)d_in[14];
    const float* by  = (const float*)d_in[15];
    float* y = (float*)d_out;

    char* ws = (char*)d_ws;
    // layout: Wpack 12,582,912 | xe_all 33,554,432 | hbuf 262,144 | arrive 524,288 | hfinal 262,144
    unsigned short* Wpack  = (unsigned short*)ws;
    unsigned short* xe_all = (unsigned short*)(ws + 12582912);
    unsigned short* hbuf   = (unsigned short*)(ws + 12582912 + 33554432);
    unsigned*       arrive = (unsigned*)(ws + 12582912 + 33554432 + 262144);
    float*          hfinal = (float*)(ws + 12582912 + 33554432 + 262144 + 524288);

    // zero hbuf (65536 u32) + arrive (131072 u32), contiguous
    zero_kernel<<<768, 256, 0, stream>>>((unsigned*)hbuf, 196608);
    wpack_kernel<<<3072, 256, 0, stream>>>(Wxi, Whi, Wxf, Whf, Wxc, Whc, Wxo, Who, Wpack);
    xe_kernel<<<32768, 128, 0, stream>>>(x, emb, xe_all);

    const unsigned short* xe_p = xe_all;
    const unsigned short* Wp_p = Wpack;
    unsigned short* hb_p = hbuf;
    float* hf_p = hfinal;
    unsigned* ar_p = arrive;
    void* args[] = {&xe_p, &Wp_p, &hb_p, &hf_p, &ar_p,
                    (void*)&bi, (void*)&bfp, (void*)&bc, (void*)&bo};
    hipLaunchCooperativeKernel((void*)lstm_kernel, dim3(NBLK), dim3(THREADS), args, 0, stream);

    out_kernel<<<32, 256, 0, stream>>>(hfinal, Why, by, y);
}